// Round 9
// baseline (610.003 us; speedup 1.0000x reference)
//
#include <hip/hip_runtime.h>
#include <hip/hip_bf16.h>

#define N_NODES 50000
#define N_EDGES 800000
#define DIM 64
#define NB 391      // dst buckets of 128 nodes: ceil(50000/128)
#define NBLK 128    // blocks in bucketize pass
#define CHUNK 6250  // N_EDGES / NBLK (exact)
#define CAP 4096    // LDS staging capacity per bucket segment (avg ~2048)

// ---------- helpers ----------
__device__ __forceinline__ float bf2f(unsigned short u) {
  return __uint_as_float(((unsigned int)u) << 16);
}
__device__ __forceinline__ unsigned short f2bf(float f) {
  unsigned int x = __float_as_uint(f);
  unsigned int r = (x + 0x7fffu + ((x >> 16) & 1u)) >> 16;  // RNE
  return (unsigned short)r;
}

// ---------- dtype detection (flags[0]=bf16 inputs, flags[1]=int64 indices) ----------
__global__ void k_detect(const unsigned short* __restrict__ feat,
                         const unsigned int* __restrict__ eidx,
                         int* __restrict__ flags) {
  int lane = threadIdx.x;  // 64 threads
  float v = bf2f(feat[2 * lane]);
  bool big = !(fabsf(v) < 1000.0f);
  unsigned long long bb = __ballot(big);
  unsigned int w = eidx[2 * lane + 1];
  unsigned long long bz = __ballot(w == 0u);
  if (lane == 0) {
    flags[0] = (__popcll(bb) < 8) ? 1 : 0;
    flags[1] = (__popcll(bz) == 64) ? 1 : 0;
  }
}

__device__ __forceinline__ int eidx_at(const int* __restrict__ p, int k, int i64) {
  return p[i64 ? (k << 1) : k];
}

// ---------- generalized scan (n <= 65536) ----------
__global__ void k_scan1(const int* __restrict__ in, int* __restrict__ out,
                        int* __restrict__ bsum, int n) {
  __shared__ int sm[256];
  int t = threadIdx.x, b = blockIdx.x, i = b * 256 + t;
  int v = (i < n) ? in[i] : 0;
  sm[t] = v;
  __syncthreads();
  for (int off = 1; off < 256; off <<= 1) {
    int x = (t >= off) ? sm[t - off] : 0;
    __syncthreads();
    sm[t] += x;
    __syncthreads();
  }
  if (i < n) out[i] = sm[t] - v;
  if (t == 255) bsum[b] = sm[t];
}

__global__ void k_scan2(int* __restrict__ bsum, int nb) {
  __shared__ int sm[256];
  int t = threadIdx.x;
  int v = (t < nb) ? bsum[t] : 0;
  sm[t] = v;
  __syncthreads();
  for (int off = 1; off < 256; off <<= 1) {
    int x = (t >= off) ? sm[t - off] : 0;
    __syncthreads();
    sm[t] += x;
    __syncthreads();
  }
  if (t < nb) bsum[t] = sm[t] - v;
}

__global__ void k_scan3(int* __restrict__ out, const int* __restrict__ bsum, int n) {
  int t = threadIdx.x, b = blockIdx.x, i = b * 256 + t;
  if (i < n) out[i] += bsum[b];
}

// ---------- bucketed CSR build ----------
__global__ __launch_bounds__(256) void k_hist1(const int* __restrict__ eidx,
                                               const int* __restrict__ flags,
                                               int* __restrict__ hist) {
  __shared__ int h[NB];
  int t = threadIdx.x, b = blockIdx.x;
  for (int i = t; i < NB; i += 256) h[i] = 0;
  __syncthreads();
  int i64 = flags[1];
  int lo = b * CHUNK;
  for (int i = t; i < CHUNK; i += 256) {
    int d = eidx_at(eidx, N_EDGES + lo + i, i64);
    atomicAdd(&h[d >> 7], 1);
  }
  __syncthreads();
  for (int i = t; i < NB; i += 256) hist[i * NBLK + b] = h[i];
}

__global__ __launch_bounds__(256) void k_scatter(const int* __restrict__ eidx,
                                                 const int* __restrict__ flags,
                                                 const int* __restrict__ hscan,
                                                 int2* __restrict__ ebuf) {
  __shared__ int cur[NB];
  int t = threadIdx.x, b = blockIdx.x;
  for (int i = t; i < NB; i += 256) cur[i] = hscan[i * NBLK + b];
  __syncthreads();
  int i64 = flags[1];
  int lo = b * CHUNK;
  for (int i = t; i < CHUNK; i += 256) {
    int d = eidx_at(eidx, N_EDGES + lo + i, i64);
    int s = eidx_at(eidx, lo + i, i64);
    int pos = atomicAdd(&cur[d >> 7], 1);
    ebuf[pos] = make_int2(s, d);
  }
}

// fused: per-bucket degree histogram + local scan -> rowp, then LDS-staged
// CSR placement (bucket segments are dst-contiguous).
__global__ __launch_bounds__(256) void k_place(const int2* __restrict__ ebuf,
                                               const int* __restrict__ hscan,
                                               int* __restrict__ rowp,
                                               int* __restrict__ csr) {
  __shared__ int hcnt[128];
  __shared__ int sm[128];
  __shared__ int cur[128];
  __shared__ int lcsr[CAP];
  int t = threadIdx.x, b = blockIdx.x;
  int lo = hscan[b * NBLK];
  int hi = (b + 1 < NB) ? hscan[(b + 1) * NBLK] : N_EDGES;
  if (t < 128) hcnt[t] = 0;
  __syncthreads();
  for (int i = lo + t; i < hi; i += 256) atomicAdd(&hcnt[ebuf[i].y & 127], 1);
  __syncthreads();
  int v = (t < 128) ? hcnt[t] : 0;
  if (t < 128) sm[t] = v;
  __syncthreads();
  for (int off = 1; off < 128; off <<= 1) {
    int x = (t < 128 && t >= off) ? sm[t - off] : 0;
    __syncthreads();
    if (t < 128) sm[t] += x;
    __syncthreads();
  }
  int d0 = b * 128;
  if (t < 128) {
    int excl = sm[t] - v;  // exclusive local prefix
    cur[t] = excl;
    int d = d0 + t;
    if (d < N_NODES) rowp[d] = lo + excl;
  }
  if (b == NB - 1 && t == 0) rowp[N_NODES] = N_EDGES;
  __syncthreads();
  int seg_sz = hi - lo;
  if (seg_sz <= CAP) {
    for (int i = lo + t; i < hi; i += 256) {
      int2 pr = ebuf[i];
      int pos = atomicAdd(&cur[pr.y & 127], 1);
      lcsr[pos] = pr.x;
    }
    __syncthreads();
    for (int i = t; i < seg_sz; i += 256) csr[lo + i] = lcsr[i];
  } else {  // overflow fallback
    for (int i = lo + t; i < hi; i += 256) {
      int2 pr = ebuf[i];
      int pos = atomicAdd(&cur[pr.y & 127], 1);
      csr[lo + pos] = pr.x;
    }
  }
}

// ---------- h = x@W (h stored bf16), s_dst = h@a_d (fp32) ----------
// s_src is NOT precomputed: k_agg derives it from the gathered rows,
// eliminating the 51 MB/conv random ss-gather line traffic.
__global__ __launch_bounds__(256) void k_gemm(
    const void* __restrict__ xv, int x_raw, const void* __restrict__ Wv,
    const void* __restrict__ adv, int head,
    const int* __restrict__ flags, unsigned short* __restrict__ hb,
    float* __restrict__ sd) {
  const int bf = flags[0];
  const int lane = threadIdx.x & 63;
  const int wid = blockIdx.x * (blockDim.x >> 6) + (threadIdx.x >> 6);
  const int nw = gridDim.x * (blockDim.x >> 6);
  float wcol[DIM];
  float a_d;
  if (bf) {
    const unsigned short* W = (const unsigned short*)Wv + head * DIM * DIM;
    const unsigned short* pd = (const unsigned short*)adv + head * DIM;
#pragma unroll
    for (int k = 0; k < DIM; ++k) wcol[k] = bf2f(W[k * DIM + lane]);
    a_d = bf2f(pd[lane]);
  } else {
    const float* W = (const float*)Wv + head * DIM * DIM;
    const float* pd = (const float*)adv + head * DIM;
#pragma unroll
    for (int k = 0; k < DIM; ++k) wcol[k] = W[k * DIM + lane];
    a_d = pd[lane];
  }
  const int raw_bf = x_raw && bf;
  for (int row = wid; row < N_NODES; row += nw) {
    float acc = 0.f;
    if (raw_bf) {
      const ushort4* xr = (const ushort4*)((const unsigned short*)xv + row * DIM);
#pragma unroll
      for (int q = 0; q < DIM / 4; ++q) {
        ushort4 xu = xr[q];
        acc = fmaf(bf2f(xu.x), wcol[4 * q + 0], acc);
        acc = fmaf(bf2f(xu.y), wcol[4 * q + 1], acc);
        acc = fmaf(bf2f(xu.z), wcol[4 * q + 2], acc);
        acc = fmaf(bf2f(xu.w), wcol[4 * q + 3], acc);
      }
    } else {
      const float4* xr = (const float4*)((const float*)xv + row * DIM);
#pragma unroll
      for (int q = 0; q < DIM / 4; ++q) {
        float4 xf = xr[q];
        acc = fmaf(xf.x, wcol[4 * q + 0], acc);
        acc = fmaf(xf.y, wcol[4 * q + 1], acc);
        acc = fmaf(xf.z, wcol[4 * q + 2], acc);
        acc = fmaf(xf.w, wcol[4 * q + 3], acc);
      }
    }
    hb[row * DIM + lane] = f2bf(acc);
    float v = acc * a_d;  // s_dst from fp32 acc (pre-rounding, exact)
#pragma unroll
    for (int off = 32; off > 0; off >>= 1) v += __shfl_xor(v, off);
    if (lane == 0) sd[row] = v;
  }
}

// ---------- per-dst-node softmax aggregation: SINGLE gather stream ----------
// quarter-wave (16 lanes) per edge, lane loads ushort4 (4 cols) = full 128 B
// row per quarter-wave. Score computed in-register from the gathered row:
// ss = row . a_s (intra-quarter shfl reduce), e = leaky(ss + sd), p = exp(e)
// (no max subtraction: softmax is shift-invariant; scores are O(10), exp is
// safely inside fp32 range, and z >= exp(min e) >> 1e-16).
__global__ __launch_bounds__(256) void k_agg(
    const unsigned short* __restrict__ hb, const void* __restrict__ asv,
    int head, const float* __restrict__ sd, const int* __restrict__ rowp,
    const int* __restrict__ csr, float* __restrict__ out_f,
    void* __restrict__ out_final, const int* __restrict__ flags,
    int do_elu, int is_final) {
  __shared__ __align__(16) int lsrc[4][64];
  const int lane = threadIdx.x & 63;
  const int quarter = lane >> 4;
  const int c16 = lane & 15;  // this lane covers cols 4*c16 .. 4*c16+3
  const int w = threadIdx.x >> 6;
  const int node = blockIdx.x * 4 + w;
  const int base = rowp[node];
  const int deg = rowp[node + 1] - base;
  const float sdn = sd[node];

  // a_s fragment for this lane's 4 columns
  float4 av;
  if (flags[0]) {
    const unsigned short* pa = (const unsigned short*)asv + head * DIM + 4 * c16;
    av = make_float4(bf2f(pa[0]), bf2f(pa[1]), bf2f(pa[2]), bf2f(pa[3]));
  } else {
    av = *(const float4*)((const float*)asv + head * DIM + 4 * c16);
  }

  float4 acc = {0.f, 0.f, 0.f, 0.f};
  float z = 0.f;
  for (int c = 0; c < deg; c += 64) {
    const int cl = (deg - c < 64) ? (deg - c) : 64;
    if (lane < cl) lsrc[w][lane] = csr[base + c + lane];
    __builtin_amdgcn_wave_barrier();
    const int quads = (cl + 3) >> 2;
    for (int tt = 0; tt < quads; ++tt) {
      int j = 4 * tt + quarter;
      int sj = (j < cl) ? lsrc[w][j] : 0;  // safe address for inactive tail
      ushort4 hv = *(const ushort4*)(hb + sj * DIM + 4 * c16);
      float hx = bf2f(hv.x), hy = bf2f(hv.y), hz = bf2f(hv.z), hw = bf2f(hv.w);
      // ss = row . a_s : partial dot, then intra-quarter reduce (lanes xor 1,2,4,8)
      float d = fmaf(hx, av.x, fmaf(hy, av.y, fmaf(hz, av.z, hw * av.w)));
      d += __shfl_xor(d, 1);
      d += __shfl_xor(d, 2);
      d += __shfl_xor(d, 4);
      d += __shfl_xor(d, 8);
      float e = d + sdn;
      e = (e >= 0.f) ? e : 0.2f * e;
      float p = (j < cl) ? __expf(e) : 0.f;
      z += p;  // identical across the quarter's 16 lanes
      acc.x = fmaf(p, hx, acc.x);
      acc.y = fmaf(p, hy, acc.y);
      acc.z = fmaf(p, hz, acc.z);
      acc.w = fmaf(p, hw, acc.w);
    }
    __builtin_amdgcn_wave_barrier();
  }

  // combine the four quarter-wave partials (disjoint edge subsets, same cols)
  acc.x += __shfl_xor(acc.x, 16);
  acc.y += __shfl_xor(acc.y, 16);
  acc.z += __shfl_xor(acc.z, 16);
  acc.w += __shfl_xor(acc.w, 16);
  z += __shfl_xor(z, 16);
  acc.x += __shfl_xor(acc.x, 32);
  acc.y += __shfl_xor(acc.y, 32);
  acc.z += __shfl_xor(acc.z, 32);
  acc.w += __shfl_xor(acc.w, 32);
  z += __shfl_xor(z, 32);

  float inv = 1.f / (z + 1e-16f);  // deg==0 -> 0, matches reference
  float ox = acc.x * inv, oy = acc.y * inv;
  float oz = acc.z * inv, ow = acc.w * inv;
  if (do_elu) {
    ox = (ox > 0.f) ? ox : expm1f(ox);
    oy = (oy > 0.f) ? oy : expm1f(oy);
    oz = (oz > 0.f) ? oz : expm1f(oz);
    ow = (ow > 0.f) ? ow : expm1f(ow);
  }
  if (quarter == 0) {
    int idx = node * DIM + 4 * c16;
    if (is_final) {
      if (flags[0]) {
        ushort4 o4 = {f2bf(ox), f2bf(oy), f2bf(oz), f2bf(ow)};
        *(ushort4*)((unsigned short*)out_final + idx) = o4;
      } else {
        float4 o4 = {ox, oy, oz, ow};
        *(float4*)((float*)out_final + idx) = o4;
      }
    } else {
      float4 o4 = {ox, oy, oz, ow};
      *(float4*)(out_f + idx) = o4;
    }
  }
}

// ---------- launch ----------
extern "C" void kernel_launch(void* const* d_in, const int* in_sizes, int n_in,
                              void* d_out, int out_size, void* d_ws, size_t ws_size,
                              hipStream_t stream) {
  const void* feat = d_in[0];
  const int* eidx = (const int*)d_in[1];

  float* bufA = (float*)d_ws;                                    // N*64 f32
  float* bufB = bufA + N_NODES * DIM;                            // N*64 f32
  unsigned short* hb = (unsigned short*)(bufB + N_NODES * DIM);  // N*64 bf16
  int2* ebuf = (int2*)(hb + N_NODES * DIM);                      // E int2
  float* sdst = (float*)(ebuf + N_EDGES);                        // N
  int* rowp = (int*)(sdst + N_NODES);                            // N+1
  int* csr  = rowp + N_NODES + 1;                                // E
  int* hist = csr + N_EDGES;                                     // NB*NBLK
  int* hscan = hist + NB * NBLK;                                 // NB*NBLK
  int* bsum = hscan + NB * NBLK;                                 // 256
  int* flags = bsum + 256;                                       // 2

  const int NH = NB * NBLK;                 // 50048
  const int SBH = (NH + 255) / 256;         // 196

  k_detect<<<1, 64, 0, stream>>>((const unsigned short*)feat,
                                 (const unsigned int*)eidx, flags);
  k_hist1<<<NBLK, 256, 0, stream>>>(eidx, flags, hist);
  k_scan1<<<SBH, 256, 0, stream>>>(hist, hscan, bsum, NH);
  k_scan2<<<1, 256, 0, stream>>>(bsum, SBH);
  k_scan3<<<SBH, 256, 0, stream>>>(hscan, bsum, NH);
  k_scatter<<<NBLK, 256, 0, stream>>>(eidx, flags, hscan, ebuf);
  k_place<<<NB, 256, 0, stream>>>(ebuf, hscan, rowp, csr);

  const void* xcur = feat;
  int x_raw = 1;
  float* nxt = bufA;
  float* other = bufB;
  for (int i = 0; i < 8; ++i) {
    const void* Wb = (i < 4) ? d_in[2] : d_in[5];
    const void* ab = (i < 4) ? d_in[3] : d_in[6];
    const void* db = (i < 4) ? d_in[4] : d_in[7];
    int head = i & 3;
    k_gemm<<<1024, 256, 0, stream>>>(xcur, x_raw, Wb, db, head, flags,
                                     hb, sdst);
    int elu = (i == 3 || i == 7) ? 1 : 0;
    int fin = (i == 7) ? 1 : 0;
    k_agg<<<N_NODES / 4, 256, 0, stream>>>(hb, ab, head, sdst, rowp, csr, nxt,
                                           d_out, flags, elu, fin);
    xcur = nxt; x_raw = 0;
    float* t = nxt; nxt = other; other = t;
  }
}

// Round 10
// 542.027 us; speedup vs baseline: 1.1254x; 1.1254x over previous
//
#include <hip/hip_runtime.h>
#include <hip/hip_bf16.h>

#define N_NODES 50000
#define N_EDGES 800000
#define DIM 64
#define NB 391      // dst buckets of 128 nodes: ceil(50000/128)
#define NBLK 128    // blocks in bucketize pass
#define CHUNK 6250  // N_EDGES / NBLK (exact)
#define CAP 4096    // LDS staging capacity per bucket segment (avg ~2048)

// ---------- helpers ----------
__device__ __forceinline__ float bf2f(unsigned short u) {
  return __uint_as_float(((unsigned int)u) << 16);
}
__device__ __forceinline__ unsigned short f2bf(float f) {
  unsigned int x = __float_as_uint(f);
  unsigned int r = (x + 0x7fffu + ((x >> 16) & 1u)) >> 16;  // RNE
  return (unsigned short)r;
}

// ---------- dtype detection (flags[0]=bf16 inputs, flags[1]=int64 indices) ----------
__global__ void k_detect(const unsigned short* __restrict__ feat,
                         const unsigned int* __restrict__ eidx,
                         int* __restrict__ flags) {
  int lane = threadIdx.x;  // 64 threads
  float v = bf2f(feat[2 * lane]);
  bool big = !(fabsf(v) < 1000.0f);
  unsigned long long bb = __ballot(big);
  unsigned int w = eidx[2 * lane + 1];
  unsigned long long bz = __ballot(w == 0u);
  if (lane == 0) {
    flags[0] = (__popcll(bb) < 8) ? 1 : 0;
    flags[1] = (__popcll(bz) == 64) ? 1 : 0;
  }
}

__device__ __forceinline__ int eidx_at(const int* __restrict__ p, int k, int i64) {
  return p[i64 ? (k << 1) : k];
}

// ---------- generalized scan (n <= 65536) ----------
__global__ void k_scan1(const int* __restrict__ in, int* __restrict__ out,
                        int* __restrict__ bsum, int n) {
  __shared__ int sm[256];
  int t = threadIdx.x, b = blockIdx.x, i = b * 256 + t;
  int v = (i < n) ? in[i] : 0;
  sm[t] = v;
  __syncthreads();
  for (int off = 1; off < 256; off <<= 1) {
    int x = (t >= off) ? sm[t - off] : 0;
    __syncthreads();
    sm[t] += x;
    __syncthreads();
  }
  if (i < n) out[i] = sm[t] - v;
  if (t == 255) bsum[b] = sm[t];
}

__global__ void k_scan2(int* __restrict__ bsum, int nb) {
  __shared__ int sm[256];
  int t = threadIdx.x;
  int v = (t < nb) ? bsum[t] : 0;
  sm[t] = v;
  __syncthreads();
  for (int off = 1; off < 256; off <<= 1) {
    int x = (t >= off) ? sm[t - off] : 0;
    __syncthreads();
    sm[t] += x;
    __syncthreads();
  }
  if (t < nb) bsum[t] = sm[t] - v;
}

__global__ void k_scan3(int* __restrict__ out, const int* __restrict__ bsum, int n) {
  int t = threadIdx.x, b = blockIdx.x, i = b * 256 + t;
  if (i < n) out[i] += bsum[b];
}

// ---------- bucketed CSR build ----------
__global__ __launch_bounds__(256) void k_hist1(const int* __restrict__ eidx,
                                               const int* __restrict__ flags,
                                               int* __restrict__ hist) {
  __shared__ int h[NB];
  int t = threadIdx.x, b = blockIdx.x;
  for (int i = t; i < NB; i += 256) h[i] = 0;
  __syncthreads();
  int i64 = flags[1];
  int lo = b * CHUNK;
  for (int i = t; i < CHUNK; i += 256) {
    int d = eidx_at(eidx, N_EDGES + lo + i, i64);
    atomicAdd(&h[d >> 7], 1);
  }
  __syncthreads();
  for (int i = t; i < NB; i += 256) hist[i * NBLK + b] = h[i];
}

__global__ __launch_bounds__(256) void k_scatter(const int* __restrict__ eidx,
                                                 const int* __restrict__ flags,
                                                 const int* __restrict__ hscan,
                                                 int2* __restrict__ ebuf) {
  __shared__ int cur[NB];
  int t = threadIdx.x, b = blockIdx.x;
  for (int i = t; i < NB; i += 256) cur[i] = hscan[i * NBLK + b];
  __syncthreads();
  int i64 = flags[1];
  int lo = b * CHUNK;
  for (int i = t; i < CHUNK; i += 256) {
    int d = eidx_at(eidx, N_EDGES + lo + i, i64);
    int s = eidx_at(eidx, lo + i, i64);
    int pos = atomicAdd(&cur[d >> 7], 1);
    ebuf[pos] = make_int2(s, d);
  }
}

// fused: per-bucket degree histogram + local scan -> rowp, then LDS-staged
// CSR placement (bucket segments are dst-contiguous).
__global__ __launch_bounds__(256) void k_place(const int2* __restrict__ ebuf,
                                               const int* __restrict__ hscan,
                                               int* __restrict__ rowp,
                                               int* __restrict__ csr) {
  __shared__ int hcnt[128];
  __shared__ int sm[128];
  __shared__ int cur[128];
  __shared__ int lcsr[CAP];
  int t = threadIdx.x, b = blockIdx.x;
  int lo = hscan[b * NBLK];
  int hi = (b + 1 < NB) ? hscan[(b + 1) * NBLK] : N_EDGES;
  if (t < 128) hcnt[t] = 0;
  __syncthreads();
  for (int i = lo + t; i < hi; i += 256) atomicAdd(&hcnt[ebuf[i].y & 127], 1);
  __syncthreads();
  int v = (t < 128) ? hcnt[t] : 0;
  if (t < 128) sm[t] = v;
  __syncthreads();
  for (int off = 1; off < 128; off <<= 1) {
    int x = (t < 128 && t >= off) ? sm[t - off] : 0;
    __syncthreads();
    if (t < 128) sm[t] += x;
    __syncthreads();
  }
  int d0 = b * 128;
  if (t < 128) {
    int excl = sm[t] - v;  // exclusive local prefix
    cur[t] = excl;
    int d = d0 + t;
    if (d < N_NODES) rowp[d] = lo + excl;
  }
  if (b == NB - 1 && t == 0) rowp[N_NODES] = N_EDGES;
  __syncthreads();
  int seg_sz = hi - lo;
  if (seg_sz <= CAP) {
    for (int i = lo + t; i < hi; i += 256) {
      int2 pr = ebuf[i];
      int pos = atomicAdd(&cur[pr.y & 127], 1);
      lcsr[pos] = pr.x;
    }
    __syncthreads();
    for (int i = t; i < seg_sz; i += 256) csr[lo + i] = lcsr[i];
  } else {  // overflow fallback
    for (int i = lo + t; i < hi; i += 256) {
      int2 pr = ebuf[i];
      int pos = atomicAdd(&cur[pr.y & 127], 1);
      csr[lo + pos] = pr.x;
    }
  }
}

// ---------- h = x@W (h stored bf16), s_src = h@a_s, s_dst = h@a_d (fp32) ----------
__global__ __launch_bounds__(256) void k_gemm(
    const void* __restrict__ xv, int x_raw, const void* __restrict__ Wv,
    const void* __restrict__ asv, const void* __restrict__ adv, int head,
    const int* __restrict__ flags, unsigned short* __restrict__ hb,
    float* __restrict__ ss, float* __restrict__ sd) {
  const int bf = flags[0];
  const int lane = threadIdx.x & 63;
  const int wid = blockIdx.x * (blockDim.x >> 6) + (threadIdx.x >> 6);
  const int nw = gridDim.x * (blockDim.x >> 6);
  float wcol[DIM];
  float a_s, a_d;
  if (bf) {
    const unsigned short* W = (const unsigned short*)Wv + head * DIM * DIM;
    const unsigned short* pa = (const unsigned short*)asv + head * DIM;
    const unsigned short* pd = (const unsigned short*)adv + head * DIM;
#pragma unroll
    for (int k = 0; k < DIM; ++k) wcol[k] = bf2f(W[k * DIM + lane]);
    a_s = bf2f(pa[lane]); a_d = bf2f(pd[lane]);
  } else {
    const float* W = (const float*)Wv + head * DIM * DIM;
    const float* pa = (const float*)asv + head * DIM;
    const float* pd = (const float*)adv + head * DIM;
#pragma unroll
    for (int k = 0; k < DIM; ++k) wcol[k] = W[k * DIM + lane];
    a_s = pa[lane]; a_d = pd[lane];
  }
  const int raw_bf = x_raw && bf;
  for (int row = wid; row < N_NODES; row += nw) {
    float acc = 0.f;
    if (raw_bf) {
      const ushort4* xr = (const ushort4*)((const unsigned short*)xv + row * DIM);
#pragma unroll
      for (int q = 0; q < DIM / 4; ++q) {
        ushort4 xu = xr[q];
        acc = fmaf(bf2f(xu.x), wcol[4 * q + 0], acc);
        acc = fmaf(bf2f(xu.y), wcol[4 * q + 1], acc);
        acc = fmaf(bf2f(xu.z), wcol[4 * q + 2], acc);
        acc = fmaf(bf2f(xu.w), wcol[4 * q + 3], acc);
      }
    } else {
      const float4* xr = (const float4*)((const float*)xv + row * DIM);
#pragma unroll
      for (int q = 0; q < DIM / 4; ++q) {
        float4 xf = xr[q];
        acc = fmaf(xf.x, wcol[4 * q + 0], acc);
        acc = fmaf(xf.y, wcol[4 * q + 1], acc);
        acc = fmaf(xf.z, wcol[4 * q + 2], acc);
        acc = fmaf(xf.w, wcol[4 * q + 3], acc);
      }
    }
    hb[row * DIM + lane] = f2bf(acc);
    float u = acc * a_s, v = acc * a_d;  // scores from fp32 acc (pre-rounding)
#pragma unroll
    for (int off = 32; off > 0; off >>= 1) {
      u += __shfl_xor(u, off);
      v += __shfl_xor(v, off);
    }
    if (lane == 0) { ss[row] = u; sd[row] = v; }
  }
}

// ---------- per-dst-node softmax aggregation (one wave per node, R6/R8 proven) ----------
// quad-gather: quarter-wave (16 lanes) per edge, each lane loads ushort4
// (4 cols, 8 B) -> one full 128 B h-row per quarter-wave, 4 edges & 512 B
// per load instruction. Softmax without max-subtraction (shift-invariant;
// scores are O(10) so fp32 exp is safe — verified bit-identical absmax in R9).
__device__ __forceinline__ void quad_accum(const unsigned short* __restrict__ hb,
                                           const int2* __restrict__ lps, int cl,
                                           int quarter, int c16, float4& acc) {
  const int quads = (cl + 3) >> 2;
#pragma unroll 4
  for (int tt = 0; tt < quads; ++tt) {
    int j = 4 * tt + quarter;  // tail entries have p=0,s=0 -> contribute 0
    int2 pv = lps[j];          // LDS broadcast within quarter-wave
    float pj = __int_as_float(pv.x);
    int sj = pv.y;
    ushort4 hv = *(const ushort4*)(hb + sj * DIM + 4 * c16);
    acc.x = fmaf(pj, bf2f(hv.x), acc.x);
    acc.y = fmaf(pj, bf2f(hv.y), acc.y);
    acc.z = fmaf(pj, bf2f(hv.z), acc.z);
    acc.w = fmaf(pj, bf2f(hv.w), acc.w);
  }
}

__global__ __launch_bounds__(256) void k_agg(
    const unsigned short* __restrict__ hb, const float* __restrict__ ss,
    const float* __restrict__ sd, const int* __restrict__ rowp,
    const int* __restrict__ csr, float* __restrict__ out_f,
    void* __restrict__ out_final, const int* __restrict__ flags,
    int do_elu, int is_final) {
  __shared__ __align__(16) int2 lps[4][64];  // {p bits, src}
  const int lane = threadIdx.x & 63;
  const int quarter = lane >> 4;
  const int c16 = lane & 15;  // this lane covers cols 4*c16 .. 4*c16+3
  const int w = threadIdx.x >> 6;
  const int node = blockIdx.x * 4 + w;
  const int base = rowp[node];
  const int deg = rowp[node + 1] - base;
  const float sdn = sd[node];

  float4 acc = {0.f, 0.f, 0.f, 0.f};
  float z;
  if (deg <= 64) {
    int s = 0;
    float p = 0.f;
    if (lane < deg) {
      s = csr[base + lane];
      float t = ss[s] + sdn;
      t = (t >= 0.f) ? t : 0.2f * t;
      p = __expf(t);  // no max-subtraction needed (shift-invariant, scores O(10))
    }
    z = p;
#pragma unroll
    for (int off = 32; off > 0; off >>= 1) z += __shfl_xor(z, off);
    lps[w][lane] = make_int2(__float_as_int(p), s);
    __builtin_amdgcn_wave_barrier();
    quad_accum(hb, &lps[w][0], deg, quarter, c16, acc);
    __builtin_amdgcn_wave_barrier();
  } else {
    z = 0.f;
    for (int c = 0; c < deg; c += 64) {
      int j = c + lane;
      float p = 0.f; int s = 0;
      if (j < deg) {
        s = csr[base + j];
        float sc = ss[s] + sdn;
        sc = (sc >= 0.f) ? sc : 0.2f * sc;
        p = __expf(sc);
      }
      lps[w][lane] = make_int2(__float_as_int(p), s);
      __builtin_amdgcn_wave_barrier();
      z += p;
      const int cl = (deg - c < 64) ? (deg - c) : 64;
      quad_accum(hb, &lps[w][0], cl, quarter, c16, acc);
      __builtin_amdgcn_wave_barrier();
    }
#pragma unroll
    for (int off = 32; off > 0; off >>= 1) z += __shfl_xor(z, off);
  }

  // combine the four quarter-wave partial sums (same cols, disjoint edges)
  acc.x += __shfl_xor(acc.x, 16);
  acc.y += __shfl_xor(acc.y, 16);
  acc.z += __shfl_xor(acc.z, 16);
  acc.w += __shfl_xor(acc.w, 16);
  acc.x += __shfl_xor(acc.x, 32);
  acc.y += __shfl_xor(acc.y, 32);
  acc.z += __shfl_xor(acc.z, 32);
  acc.w += __shfl_xor(acc.w, 32);

  float inv = 1.f / (z + 1e-16f);  // deg==0 -> 0, matches reference
  float ox = acc.x * inv, oy = acc.y * inv;
  float oz = acc.z * inv, ow = acc.w * inv;
  if (do_elu) {
    ox = (ox > 0.f) ? ox : expm1f(ox);
    oy = (oy > 0.f) ? oy : expm1f(oy);
    oz = (oz > 0.f) ? oz : expm1f(oz);
    ow = (ow > 0.f) ? ow : expm1f(ow);
  }
  if (quarter == 0) {
    int idx = node * DIM + 4 * c16;
    if (is_final) {
      if (flags[0]) {
        ushort4 o4 = {f2bf(ox), f2bf(oy), f2bf(oz), f2bf(ow)};
        *(ushort4*)((unsigned short*)out_final + idx) = o4;
      } else {
        float4 o4 = {ox, oy, oz, ow};
        *(float4*)((float*)out_final + idx) = o4;
      }
    } else {
      float4 o4 = {ox, oy, oz, ow};
      *(float4*)(out_f + idx) = o4;
    }
  }
}

// ---------- launch ----------
extern "C" void kernel_launch(void* const* d_in, const int* in_sizes, int n_in,
                              void* d_out, int out_size, void* d_ws, size_t ws_size,
                              hipStream_t stream) {
  const void* feat = d_in[0];
  const int* eidx = (const int*)d_in[1];

  float* bufA = (float*)d_ws;                                    // N*64 f32
  float* bufB = bufA + N_NODES * DIM;                            // N*64 f32
  unsigned short* hb = (unsigned short*)(bufB + N_NODES * DIM);  // N*64 bf16
  int2* ebuf = (int2*)(hb + N_NODES * DIM);                      // E int2
  float* ssrc = (float*)(ebuf + N_EDGES);                        // N
  float* sdst = ssrc + N_NODES;                                  // N
  int* rowp = (int*)(sdst + N_NODES);                            // N+1
  int* csr  = rowp + N_NODES + 1;                                // E
  int* hist = csr + N_EDGES;                                     // NB*NBLK
  int* hscan = hist + NB * NBLK;                                 // NB*NBLK
  int* bsum = hscan + NB * NBLK;                                 // 256
  int* flags = bsum + 256;                                       // 2

  const int NH = NB * NBLK;                 // 50048
  const int SBH = (NH + 255) / 256;         // 196

  k_detect<<<1, 64, 0, stream>>>((const unsigned short*)feat,
                                 (const unsigned int*)eidx, flags);
  k_hist1<<<NBLK, 256, 0, stream>>>(eidx, flags, hist);
  k_scan1<<<SBH, 256, 0, stream>>>(hist, hscan, bsum, NH);
  k_scan2<<<1, 256, 0, stream>>>(bsum, SBH);
  k_scan3<<<SBH, 256, 0, stream>>>(hscan, bsum, NH);
  k_scatter<<<NBLK, 256, 0, stream>>>(eidx, flags, hscan, ebuf);
  k_place<<<NB, 256, 0, stream>>>(ebuf, hscan, rowp, csr);

  const void* xcur = feat;
  int x_raw = 1;
  float* nxt = bufA;
  float* other = bufB;
  for (int i = 0; i < 8; ++i) {
    const void* Wb = (i < 4) ? d_in[2] : d_in[5];
    const void* ab = (i < 4) ? d_in[3] : d_in[6];
    const void* db = (i < 4) ? d_in[4] : d_in[7];
    int head = i & 3;
    k_gemm<<<1024, 256, 0, stream>>>(xcur, x_raw, Wb, ab, db, head, flags,
                                     hb, ssrc, sdst);
    int elu = (i == 3 || i == 7) ? 1 : 0;
    int fin = (i == 7) ? 1 : 0;
    k_agg<<<N_NODES / 4, 256, 0, stream>>>(hb, ssrc, sdst, rowp, csr, nxt,
                                           d_out, flags, elu, fin);
    xcur = nxt; x_raw = 0;
    float* t = nxt; nxt = other; other = t;
  }
}